// Round 3
// baseline (775.277 us; speedup 1.0000x reference)
//
#include <hip/hip_runtime.h>

#define NA 51
#define TPB 256
#define KCLAMP 52

// 4-byte-aligned vector types: gfx950 global loads/stores support dword
// alignment for dwordx2/dwordx4 (row stride 204 B is not 16B-aligned).
typedef float f4 __attribute__((ext_vector_type(4), aligned(4)));
typedef float f2 __attribute__((ext_vector_type(2), aligned(4)));

// C51 Bellman projection, thread-per-row, NO LDS.
//   s = reward*2.5, k = floor(s) (clamped to +/-52, equivalent), f = frac(s)
//   out[i] = (1-f)*p[i-k]*[0<=i-k<=50] + f*p[i-k-1]*[...] + (i==0)*m_lo + (i==50)*m_hi
// Each lane loads its own row (51 floats) and its gather window (52 floats at
// rowbase-k-1) directly into registers via 4B-aligned dwordx4 — both are
// contiguous per lane, all register indices static. A wave's 26 load instrs
// cover its own contiguous 13 KB tile -> full L2 line utilization. No LDS =>
// no barriers, no lgkmcnt chains, no vmcnt(0) drain, occupancy VGPR-bound
// (~125 regs -> 16 waves/CU vs the previous LDS-capped 12).
// Window reads can stray +/-212 B outside the row, which is only out-of-bounds
// for the tensor's first/last ~2 rows: the first and last BLOCK (uniform
// branch) use a per-element index-clamped path (always in-row => safe).
// Output is written once and never read: nontemporal stores keep the streamed
// output from evicting probs (204 MB, Infinity-Cache-resident) from L3.
__global__ __launch_bounds__(TPB, 4) void c51_bellman_kernel(
    const float* __restrict__ reward,
    const float* __restrict__ probs,
    float* __restrict__ out,
    int bs)
{
    const int r = blockIdx.x * TPB + threadIdx.x;
    const bool edge = (blockIdx.x == 0) | (blockIdx.x == (int)gridDim.x - 1);
    if (r >= bs) return;

    const float s  = reward[r] * 2.5f;   // r / 0.4
    const float kf = floorf(s);
    const float f  = s - kf;
    int k = (int)kf;
    k = min(max(k, -KCLAMP), KCLAMP);    // out-of-range k: all terms zero either way

    const float* rp = probs + (size_t)r * NA;

    // ---- own row -> regs (12 x dwordx4 + dwordx2 + dword), for clamp masses ----
    float row[51];
    #pragma unroll
    for (int m = 0; m < 12; ++m) *(f4*)&row[4 * m] = *(const f4*)&rp[4 * m];
    *(f2*)&row[48] = *(const f2*)&rp[48];
    row[50] = rp[50];

    float m_lo = 0.0f, m_hi = 0.0f;
    #pragma unroll
    for (int j = 0; j < NA; ++j) {
        const float t = (float)j + s;
        if (t < 0.0f)  m_lo += row[j];
        if (t > 50.0f) m_hi += row[j];
    }

    // ---- gather window w[m] = p[m-k-1] -> regs (13 x dwordx4) ----
    float w[52];
    if (!edge) {
        const float* wb = rp - k - 1;    // may stray into neighbor rows: garbage
        #pragma unroll                   // there is masked to zero below
        for (int m = 0; m < 13; ++m) *(f4*)&w[4 * m] = *(const f4*)&wb[4 * m];
    } else {
        // first/last block only: clamp per-element index into own row (safe);
        // masked-in positions have 0 <= m-k-1 <= 50, where clamp is a no-op.
        #pragma unroll
        for (int m = 0; m < 52; ++m)
            w[m] = rp[min(max(m - k - 1, 0), NA - 1)];
    }

    // ---- projection: out[i] = (1-f)*cur + f*prev (+ masses at the ends) ----
    //   w1 = (i+f<=50)?1-f:0  ->  1-f for i<50;  (f==0)?1:0 at i=50
    //   w2 = (i-1+f>=0)?f:0   ->  0 at i==0;     f for i>=1
    const float w1 = 1.0f - f;
    float prev = ((unsigned)(-k - 1) <= 50u) ? w[0] : 0.0f;
    #pragma unroll
    for (int i = 0; i < NA; ++i) {
        const float cur = ((unsigned)(i - k) <= 50u) ? w[i + 1] : 0.0f;
        float o;
        if (i == 0)           o = w1 * cur + m_lo;
        else if (i == NA - 1) o = ((f == 0.0f) ? cur : f * prev) + m_hi;
        else                  o = w1 * cur + f * prev;
        w[i] = o;            // w[i] is dead here (its value lives on in prev)
        prev = cur;
    }

    // ---- store own row: nontemporal dwordx4 (streamed-once output) ----
    float* op = out + (size_t)r * NA;
    #pragma unroll
    for (int m = 0; m < 12; ++m)
        __builtin_nontemporal_store(*(const f4*)&w[4 * m], (f4*)&op[4 * m]);
    __builtin_nontemporal_store(*(const f2*)&w[48], (f2*)&op[48]);
    __builtin_nontemporal_store(w[50], &op[50]);
}

extern "C" void kernel_launch(void* const* d_in, const int* in_sizes, int n_in,
                              void* d_out, int out_size, void* d_ws, size_t ws_size,
                              hipStream_t stream) {
    const float* reward = (const float*)d_in[0];
    const float* probs  = (const float*)d_in[1];
    // d_in[2] = atom_values: unused — atom j sits exactly at index j in idx-space
    float* out = (float*)d_out;
    const int bs = in_sizes[0];

    const int blocks = (bs + TPB - 1) / TPB;
    c51_bellman_kernel<<<blocks, TPB, 0, stream>>>(reward, probs, out, bs);
}

// Round 6
// 389.400 us; speedup vs baseline: 1.9910x; 1.9910x over previous
//
#include <hip/hip_runtime.h>

#define NA 51
#define ROWS 64                       // one wave per block
#define GUARD 56                      // floats of guard each side (k clamped to +/-52)
#define NDATA (ROWS * NA)             // 3264 floats = 13056 B
#define BUFSZ (GUARD + NDATA + GUARD) // 3376 floats = 13504 B
#define KCLAMP 52
#define NBLK 1536                     // 6 blocks/CU x 256 CU (2x13504 B LDS -> 6 blocks/CU)

// native vector type for nontemporal builtins (HIP float4 is a class -> rejected)
typedef float v4 __attribute__((ext_vector_type(4), aligned(16)));

// counted vmcnt wait + scheduler fence (rule #18: stop reg-only hoisting past asm)
#define WAITV(N) do { asm volatile("s_waitcnt vmcnt(" #N ")" ::: "memory"); \
                      __builtin_amdgcn_sched_barrier(0); } while (0)

// C51 Bellman projection, persistent single-wave blocks, double-buffered LDS.
//   s = reward*2.5, k = floor(s) clamped to +/-52 (equivalent), f = frac(s)
//   out[i] = (1-f)*p[i-k]*[0<=i-k<=50] + f*p[i-k-1]*[...] + (i==0)*m_lo + (i==50)*m_hi
//
// Pipeline per half: issue the NEXT tile's 14 vmem LOADS (1 reward + 13
// global_load_lds) into the other buffer, then WAITV(14). Round-5 lesson:
// vmcnt retires in order only AMONG READS (stores may complete out of order
// w.r.t. reads, cf. gfx10's separate vscnt), so a wait count may only assume
// ordering within the load stream: vmcnt(14) bounds total outstanding <= 14,
// hence outstanding LOADS are a suffix of <= 14 = exactly the next tile's
// group -> current tile's loads provably complete, regardless of store
// completion order. Never vmcnt(0) in steady state. Two DISTINCT __shared__
// arrays so alias analysis can't insert a conservative drain between
// prefetch(bufB) and ds_read(bufA).
// Tail 768 B staged with an exec-masked width-16 global_load_lds (tid<48):
// width-12's LDS lane stride is unmeasured (round-5 suspect #2) — avoid.
// Copy-out keeps the coalesced LDS->float4 transpose (round-3 lesson: lane-
// major register stores = 4.6x write amplification); stores are nontemporal
// (full-line coalesced => amplification-safe) so the once-written output
// stream doesn't evict L3-resident probs.
__global__ __launch_bounds__(ROWS, 2) void c51_bellman_kernel(
    const float* __restrict__ reward,
    const float* __restrict__ probs,
    float* __restrict__ out,
    int bs)
{
    __shared__ __align__(16) float bufA[BUFSZ];
    __shared__ __align__(16) float bufB[BUFSZ];
    float* const dA = bufA + GUARD;   // GUARD*4 = 224 B -> 16B-aligned data
    float* const dB = bufB + GUARD;
    const int tid   = threadIdx.x;
    const int gs    = gridDim.x;
    const int nfull = bs / ROWS;      // full 64-row tiles
    const int rem   = bs - nfull * ROWS;

    // ---- helpers (inlined) ----
    auto issueL = [&](long tile, float* dst) {
        const char* src = (const char*)probs + (size_t)tile * (NDATA * 4);
        #pragma unroll
        for (int c = 0; c < 12; ++c) {
            __builtin_amdgcn_global_load_lds(
                (const __attribute__((address_space(1))) void*)
                    (unsigned long long)(src + c * 1024 + tid * 16),
                (__attribute__((address_space(3))) void*)
                    (unsigned long long)(dst + c * 256),
                16, 0, 0);
        }
        // tail 768 B = 48 lanes x 16 B, exec-masked single instruction
        // (masked lanes issue no LDS write; still 1 vmcnt op for the wave)
        if (tid < 48) {
            __builtin_amdgcn_global_load_lds(
                (const __attribute__((address_space(1))) void*)
                    (unsigned long long)(src + 12288 + tid * 16),
                (__attribute__((address_space(3))) void*)
                    (unsigned long long)(dst + 3072),
                16, 0, 0);
        }
    };

    auto computeT = [&](float* data, float rw) {
        const float s  = rw * 2.5f;          // r / 0.4
        const float kf = floorf(s);
        const float f  = s - kf;
        int k = (int)kf;
        k = min(max(k, -KCLAMP), KCLAMP);    // out-of-range k: all terms zero anyway
        const float* rp = data + tid * NA;   // lane stride 51 (odd) -> conflict-free

        // pass A: clamp masses
        float m_lo = 0.0f, m_hi = 0.0f;
        #pragma unroll
        for (int j = 0; j < NA; ++j) {
            const float pj = rp[j];
            const float t  = (float)j + s;
            if (t < 0.0f)  m_lo += pj;
            if (t > 50.0f) m_hi += pj;
        }

        // pass B: guarded window w[m] = p[m-k-1] (garbage in guards, masked below).
        // Whole window read before any write; one wave => all lanes' cross-row
        // reads complete before any lane's in-place writes (in-order DS).
        const float* wb = rp - k - 1;
        float w[52];
        #pragma unroll
        for (int m = 0; m < 52; ++m) w[m] = wb[m];

        float* wp = data + tid * NA;
        const float w1 = 1.0f - f;
        float prev = ((unsigned)(-k - 1) <= 50u) ? w[0] : 0.0f;
        #pragma unroll
        for (int i = 0; i < NA; ++i) {
            const float cur = ((unsigned)(i - k) <= 50u) ? w[i + 1] : 0.0f;
            float o;
            if (i == 0)           o = w1 * cur + m_lo;
            else if (i == NA - 1) o = ((f == 0.0f) ? cur : f * prev) + m_hi;
            else                  o = w1 * cur + f * prev;
            wp[i] = o;                        // own row only; reads already issued
            prev = cur;
        }
    };

    auto storeT = [&](const float* data, long tile) {
        const v4* l4 = (const v4*)data;
        v4* o4 = (v4*)(out + (size_t)tile * NDATA);
        #pragma unroll
        for (int m = 0; m < 12; ++m)
            __builtin_nontemporal_store(l4[m * 64 + tid], o4 + m * 64 + tid);
        if (tid < 48)                         // 816 float4 total = 12*64 + 48
            __builtin_nontemporal_store(l4[768 + tid], o4 + 768 + tid);
    };

    // ---- persistent double-buffered pipeline over full tiles ----
    long t = blockIdx.x;
    if (t < nfull) {
        float rwA = reward[t * ROWS + tid];
        issueL(t, dA);
        for (;;) {
            // --- half A: tile t resident in bufA ---
            const long tB = t + gs;
            const bool hB = tB < nfull;
            float rwB = 0.0f;
            if (hB) { rwB = reward[tB * ROWS + tid]; issueL(tB, dB); WAITV(14); }
            else    { WAITV(0); }
            computeT(dA, rwA);
            storeT(dA, t);
            if (!hB) break;

            // --- half B: tile tB resident in bufB ---
            const long tA2 = tB + gs;
            const bool hA = tA2 < nfull;
            if (hA) { rwA = reward[tA2 * ROWS + tid]; issueL(tA2, dA); WAITV(14); }
            else    { WAITV(0); }
            computeT(dB, rwB);
            storeT(dB, tB);
            if (!hA) break;
            t = tA2;
        }
    }

    // ---- ragged tail rows (bs % 64 != 0; unused at bs=1e6): block 0, lane/row ----
    if (rem && blockIdx.x == 0) {
        const int r = nfull * ROWS + tid;
        if (r < bs) {
            const float s  = reward[r] * 2.5f;
            const float kf = floorf(s);
            const float f  = s - kf;
            int k = (int)kf; k = min(max(k, -KCLAMP), KCLAMP);
            const float* rp = probs + (size_t)r * NA;
            float row[NA];
            #pragma unroll
            for (int j = 0; j < NA; ++j) row[j] = rp[j];
            float m_lo = 0.0f, m_hi = 0.0f;
            #pragma unroll
            for (int j = 0; j < NA; ++j) {
                const float tt = (float)j + s;
                if (tt < 0.0f)  m_lo += row[j];
                if (tt > 50.0f) m_hi += row[j];
            }
            float w[52];
            #pragma unroll
            for (int m = 0; m < 52; ++m)       // clamped index: masked-in slots unaffected
                w[m] = row[min(max(m - k - 1, 0), NA - 1)];
            float* op = out + (size_t)r * NA;
            const float w1 = 1.0f - f;
            float prev = ((unsigned)(-k - 1) <= 50u) ? w[0] : 0.0f;
            #pragma unroll
            for (int i = 0; i < NA; ++i) {
                const float cur = ((unsigned)(i - k) <= 50u) ? w[i + 1] : 0.0f;
                float o;
                if (i == 0)           o = w1 * cur + m_lo;
                else if (i == NA - 1) o = ((f == 0.0f) ? cur : f * prev) + m_hi;
                else                  o = w1 * cur + f * prev;
                op[i] = o;
                prev = cur;
            }
        }
    }
}

extern "C" void kernel_launch(void* const* d_in, const int* in_sizes, int n_in,
                              void* d_out, int out_size, void* d_ws, size_t ws_size,
                              hipStream_t stream) {
    const float* reward = (const float*)d_in[0];
    const float* probs  = (const float*)d_in[1];
    // d_in[2] = atom_values: unused — atom j sits exactly at index j in idx-space
    float* out = (float*)d_out;
    const int bs = in_sizes[0];

    const int nfull = bs / ROWS;
    int blocks = nfull < NBLK ? nfull : NBLK;
    if (blocks < 1) blocks = 1;   // bs < 64: tail path only
    c51_bellman_kernel<<<blocks, ROWS, 0, stream>>>(reward, probs, out, bs);
}